// Round 6
// baseline (195.655 us; speedup 1.0000x reference)
//
#include <hip/hip_runtime.h>
#include <stdint.h>

#define TOK 8192      // B*T = 4*2048
#define EMB 1024
#define HD 64         // head_out
#define HEADS 16
#define KVBLK 64

typedef float f32x4 __attribute__((ext_vector_type(4)));
typedef short s16x8 __attribute__((ext_vector_type(8)));

__device__ __forceinline__ unsigned short f2bf(float f) {
    unsigned u = __float_as_uint(f);
    unsigned r = (u + 0x7FFFu + ((u >> 16) & 1u)) >> 16;  // RNE
    return (unsigned short)r;
}

__device__ __forceinline__ unsigned cvt_pk_bf16(float lo, float hi) {
    unsigned r;
    asm("v_cvt_pk_bf16_f32 %0, %1, %2" : "=v"(r) : "v"(lo), "v"(hi));
    return r;
}

__device__ __forceinline__ s16x8 frag4(unsigned a, unsigned b, unsigned c, unsigned d) {
    int4 t = make_int4((int)a, (int)b, (int)c, (int)d);
    return __builtin_bit_cast(s16x8, t);
}

// ---------------- prep: W (fp32, 3x64x1024) -> wb (bf16, 192x1024), biases -> bb[192]
__global__ __launch_bounds__(256) void prep_kernel(
        const float* __restrict__ Wq, const float* __restrict__ bq,
        const float* __restrict__ Wk, const float* __restrict__ bk,
        const float* __restrict__ Wv, const float* __restrict__ bv,
        unsigned short* __restrict__ wb, float* __restrict__ bb) {
    int gid = blockIdx.x * 256 + threadIdx.x;       // 0 .. 192*1024-1
    int row = gid >> 10, col = gid & 1023;
    const float QS = 1.4426950408889634f / 32.0f;   // log2(e) / sqrt(1024)
    float w;
    if (row < 64)       w = Wq[row * 1024 + col] * QS;
    else if (row < 128) w = Wk[(row - 64) * 1024 + col];
    else                w = Wv[(row - 128) * 1024 + col];
    wb[gid] = f2bf(w);
    if (gid < 192) {
        float b;
        if (gid < 64)       b = bq[gid] * QS;
        else if (gid < 128) b = bk[gid - 64];
        else                b = bv[gid - 128];
        bb[gid] = b;
    }
}

// ---------------- proj: x @ wb^T + bb -> qw, kw (8192x64 bf16), vt2 (tiled V^T)
// vt2 layout: [kv/64][dv(64)][kv%64] -- dense 8KB tile per 64-kv block.
#define XPAD 1040   // shorts per LDS row
__global__ __launch_bounds__(768) void proj_kernel(
        const float* __restrict__ x, const unsigned short* __restrict__ wb,
        const float* __restrict__ bb,
        unsigned short* __restrict__ qw, unsigned short* __restrict__ kw,
        unsigned short* __restrict__ vt2) {
    __shared__ __align__(16) unsigned short xb[16][XPAD];
    int tid = threadIdx.x;
    int row0 = blockIdx.x * 16;

    if (tid < 512) {
        #pragma unroll
        for (int i = 0; i < 8; ++i) {
            int flat = i * 2048 + tid * 4;           // 16x1024 elems
            int r = flat >> 10, col = flat & 1023;
            float4 f = *(const float4*)(x + (size_t)(row0 + r) * EMB + col);
            uint2 p;
            p.x = cvt_pk_bf16(f.x, f.y);
            p.y = cvt_pk_bf16(f.z, f.w);
            *(uint2*)(&xb[r][col]) = p;
        }
    }
    __syncthreads();

    int wave = tid >> 6;            // 0..11 = output col-tile
    int lane = tid & 63;
    int c = lane & 15, g = lane >> 4;

    f32x4 acc = {};
    const unsigned short* bp0 = wb + (size_t)(wave * 16 + c) * EMB;
    #pragma unroll 8
    for (int ks = 0; ks < EMB / 32; ++ks) {
        s16x8 a = *(const s16x8*)(&xb[c][ks * 32 + g * 8]);
        s16x8 b = *(const s16x8*)(bp0 + ks * 32 + g * 8);
        acc = __builtin_amdgcn_mfma_f32_16x16x32_bf16(a, b, acc, 0, 0, 0);
    }
    float bias = bb[wave * 16 + c];
    acc[0] += bias; acc[1] += bias; acc[2] += bias; acc[3] += bias;
    if (wave < 4) {
        int col = wave * 16 + c;
        #pragma unroll
        for (int r = 0; r < 4; ++r)
            qw[(size_t)(row0 + g * 4 + r) * HD + col] = f2bf(acc[r]);
    } else if (wave < 8) {
        int col = (wave - 4) * 16 + c;
        #pragma unroll
        for (int r = 0; r < 4; ++r)
            kw[(size_t)(row0 + g * 4 + r) * HD + col] = f2bf(acc[r]);
    } else {
        int d = (wave - 8) * 16 + c;
        uint2 pack;
        pack.x = cvt_pk_bf16(acc[0], acc[1]);
        pack.y = cvt_pk_bf16(acc[2], acc[3]);
        *(uint2*)(vt2 + (size_t)(row0 >> 6) * 4096 + d * 64 + (row0 & 63) + g * 4) = pack;
    }
}

// ---------------- attn: swapped-QK flash, no max, no LDS, 64 q-rows per wave,
// register-pipelined K (next-iter K prefetched at body top; one full body of
// compute (~1100 cyc) covers the L2 latency). st computed per qt-pair to cap VGPR.
template <int S>
__global__ __launch_bounds__(256, 2) void attn_kernel(
        const unsigned short* __restrict__ qw, const unsigned short* __restrict__ kw,
        const unsigned short* __restrict__ vt2,
        float* __restrict__ po, float* __restrict__ pl) {
    constexpr int KVS = TOK / S;
    constexpr int NIT = KVS / KVBLK;     // 8 for S=16 (even: 2x-unrolled pipeline)
    constexpr int QB = TOK / 256;        // 32 qblocks of 256 rows
    int wave = threadIdx.x >> 6;
    int lane = threadIdx.x & 63;
    int c = lane & 15, g = lane >> 4;
    int qb = blockIdx.x % QB;
    int split = blockIdx.x / QB;
    int wq0 = qb * 256 + wave * 64;      // this wave's 64 q-rows
    int kv0 = split * KVS;
    int moff = (((g & 1) << 1) | (g >> 1)) * 8;  // permuted kv chunk within 32
    bool odd = (g & 1) != 0;

    // Q B-frags: 4 q-tiles x 2 k-halves (loop-invariant)
    s16x8 aq[4][2];
    #pragma unroll
    for (int qt = 0; qt < 4; ++qt)
        #pragma unroll
        for (int kh = 0; kh < 2; ++kh)
            aq[qt][kh] = *(const s16x8*)(qw + (size_t)(wq0 + qt * 16 + c) * HD + kh * 32 + g * 8);

    f32x4 o[4][4] = {};
    float l[4] = {};

    auto loadK = [&](s16x8 (&kf)[2][4], int kvi) {
        #pragma unroll
        for (int kh = 0; kh < 2; ++kh)
            #pragma unroll
            for (int t = 0; t < 4; ++t)
                kf[kh][t] = *(const s16x8*)(kw + (size_t)(kvi + t * 16 + c) * HD + kh * 32 + g * 8);
    };

    auto body = [&](s16x8 (&kf)[2][4], int kvi) {
        // V frags for this iter (consumed ~500 cyc later -> L2 latency hidden)
        const unsigned short* vtile = vt2 + (size_t)(kvi >> 6) * 4096;
        s16x8 v0[4], v1[4];
        #pragma unroll
        for (int t = 0; t < 4; ++t) {
            v0[t] = *(const s16x8*)(vtile + (t * 16 + c) * 64 + moff);
            v1[t] = *(const s16x8*)(vtile + (t * 16 + c) * 64 + 32 + moff);
        }
        #pragma unroll
        for (int qp = 0; qp < 2; ++qp) {
            // QK for a pair of q-tiles (st kept to 32 VGPR)
            f32x4 st[2][4] = {};
            #pragma unroll
            for (int kh = 0; kh < 2; ++kh)
                #pragma unroll
                for (int q = 0; q < 2; ++q)
                    #pragma unroll
                    for (int t = 0; t < 4; ++t)
                        st[q][t] = __builtin_amdgcn_mfma_f32_16x16x32_bf16(
                            kf[kh][t], aq[qp * 2 + q][kh], st[q][t], 0, 0, 0);
            #pragma unroll
            for (int q = 0; q < 2; ++q) {
                int qt = qp * 2 + q;
                float p[4][4];
                #pragma unroll
                for (int t = 0; t < 4; ++t)
                    #pragma unroll
                    for (int r = 0; r < 4; ++r)
                        p[t][r] = exp2f(st[q][t][r]);
                float s0 = (p[0][0] + p[0][1]) + (p[0][2] + p[0][3]);
                float s1 = (p[1][0] + p[1][1]) + (p[1][2] + p[1][3]);
                float s2 = (p[2][0] + p[2][1]) + (p[2][2] + p[2][3]);
                float s3 = (p[3][0] + p[3][1]) + (p[3][2] + p[3][3]);
                l[qt] += (s0 + s1) + (s2 + s3);
                unsigned W[4][2];
                #pragma unroll
                for (int t = 0; t < 4; ++t) {
                    W[t][0] = cvt_pk_bf16(p[t][0], p[t][1]);
                    W[t][1] = cvt_pk_bf16(p[t][2], p[t][3]);
                }
                #pragma unroll
                for (int ks = 0; ks < 2; ++ks) {
                    unsigned ael = W[2 * ks][0],     aeh = W[2 * ks][1];
                    unsigned aol = W[2 * ks + 1][0], aoh = W[2 * ks + 1][1];
                    unsigned sl = odd ? ael : aol;   // what partner g^1 needs
                    unsigned sh = odd ? aeh : aoh;
                    unsigned rl = (unsigned)__builtin_amdgcn_ds_swizzle((int)sl, 0x401F); // lane^16
                    unsigned rh = (unsigned)__builtin_amdgcn_ds_swizzle((int)sh, 0x401F);
                    unsigned f0 = odd ? rl : ael;
                    unsigned f1 = odd ? rh : aeh;
                    unsigned f2 = odd ? aol : rl;
                    unsigned f3 = odd ? aoh : rh;
                    s16x8 pa = frag4(f0, f1, f2, f3);
                    #pragma unroll
                    for (int t = 0; t < 4; ++t) {
                        s16x8 vb = ks ? v1[t] : v0[t];
                        o[qt][t] = __builtin_amdgcn_mfma_f32_16x16x32_bf16(pa, vb, o[qt][t], 0, 0, 0);
                    }
                }
            }
        }
    };

    // software pipeline: 2x-unrolled, K double-buffered in registers.
    // Final prefetch reads past this split's range -- lands in ws (valid memory),
    // never consumed.
    s16x8 kA[2][4], kB[2][4];
    loadK(kA, kv0);
    #pragma unroll 1
    for (int it2 = 0; it2 < NIT / 2; ++it2) {
        int kviA = kv0 + it2 * 2 * KVBLK;
        int kviB = kviA + KVBLK;
        loadK(kB, kviB);
        body(kA, kviA);
        loadK(kA, kviB + KVBLK);
        body(kB, kviB);
    }

    // epilogue: o[qt][t] row = g*4+r (q within tile), col = c (dv within tile t)
    #pragma unroll
    for (int qt = 0; qt < 4; ++qt) {
        #pragma unroll
        for (int t = 0; t < 4; ++t)
            #pragma unroll
            for (int r = 0; r < 4; ++r)
                po[((size_t)split * TOK + wq0 + qt * 16 + g * 4 + r) * HD + t * 16 + c] = o[qt][t][r];
        float v = l[qt];
        v += __shfl_xor(v, 16);
        v += __shfl_xor(v, 32);
        if (g == 0)
            pl[split * TOK + wq0 + qt * 16 + c] = v;
    }
}

// ---------------- combine: sum S splits, divide by total denom, tile x16 heads.
template <int S>
__global__ __launch_bounds__(256) void combine_kernel(
        const float* __restrict__ po, const float* __restrict__ pl,
        float* __restrict__ out) {
    int gid = blockIdx.x * 256 + threadIdx.x;   // 0 .. 8192*16-1
    int row = gid >> 4;
    int dc = (gid & 15) * 4;
    float4 acc = {0.f, 0.f, 0.f, 0.f};
    float denom = 0.f;
    #pragma unroll
    for (int s = 0; s < S; ++s) {
        denom += pl[s * TOK + row];
        float4 p = *(const float4*)(po + ((size_t)s * TOK + row) * HD + dc);
        acc.x += p.x; acc.y += p.y; acc.z += p.z; acc.w += p.w;
    }
    float inv = 1.0f / denom;
    acc.x *= inv; acc.y *= inv; acc.z *= inv; acc.w *= inv;
    #pragma unroll
    for (int h = 0; h < HEADS; ++h)
        *(float4*)(out + (size_t)row * EMB + h * HD + dc) = acc;
}

extern "C" void kernel_launch(void* const* d_in, const int* in_sizes, int n_in,
                              void* d_out, int out_size, void* d_ws, size_t ws_size,
                              hipStream_t stream) {
    const float* x  = (const float*)d_in[0];
    const float* Wq = (const float*)d_in[1];
    const float* bq = (const float*)d_in[2];
    const float* Wk = (const float*)d_in[3];
    const float* bk = (const float*)d_in[4];
    const float* Wv = (const float*)d_in[5];
    const float* bv = (const float*)d_in[6];
    float* out = (float*)d_out;
    char* ws = (char*)d_ws;
    unsigned short* wb  = (unsigned short*)(ws + 0x000000);  // 192x1024 bf16 = 384K
    float*          bb  = (float*)         (ws + 0x060000);  // 192 f32
    unsigned short* qw  = (unsigned short*)(ws + 0x061000);  // 8192x64 bf16 = 1M
    unsigned short* kw  = (unsigned short*)(ws + 0x161000);  // 1M
    unsigned short* vt2 = (unsigned short*)(ws + 0x261000);  // tiled V^T = 1M
    float*          po  = (float*)         (ws + 0x361000);  // S x 8192x64 f32 (2M each)

    prep_kernel<<<dim3(768), dim3(256), 0, stream>>>(Wq, bq, Wk, bk, Wv, bv, wb, bb);
    proj_kernel<<<dim3(512), dim3(768), 0, stream>>>(x, wb, bb, qw, kw, vt2);

    const size_t base = 0x361000;
    const size_t per_split = (size_t)TOK * HD * 4;       // 2 MB po
    const size_t per_pl    = (size_t)TOK * 4;            // 32 KB
    auto need = [&](int s) { return base + (size_t)s * (per_split + per_pl) + 0x100000; };

    if (ws_size >= need(16)) {
        float* pl = (float*)(ws + base + 16 * per_split);
        attn_kernel<16><<<dim3(32 * 16), dim3(256), 0, stream>>>(qw, kw, vt2, po, pl);
        combine_kernel<16><<<dim3(512), dim3(256), 0, stream>>>(po, pl, out);
    } else {
        float* pl = (float*)(ws + base + 8 * per_split);
        attn_kernel<8><<<dim3(32 * 8), dim3(256), 0, stream>>>(qw, kw, vt2, po, pl);
        combine_kernel<8><<<dim3(512), dim3(256), 0, stream>>>(po, pl, out);
    }
}

// Round 7
// 191.454 us; speedup vs baseline: 1.0219x; 1.0219x over previous
//
#include <hip/hip_runtime.h>
#include <stdint.h>

#define TOK 8192      // B*T = 4*2048
#define EMB 1024
#define HD 64         // head_out
#define HEADS 16
#define KVBLK 64

typedef float f32x4 __attribute__((ext_vector_type(4)));
typedef short s16x8 __attribute__((ext_vector_type(8)));

__device__ __forceinline__ unsigned short f2bf(float f) {
    unsigned u = __float_as_uint(f);
    unsigned r = (u + 0x7FFFu + ((u >> 16) & 1u)) >> 16;  // RNE
    return (unsigned short)r;
}

__device__ __forceinline__ unsigned cvt_pk_bf16(float lo, float hi) {
    unsigned r;
    asm("v_cvt_pk_bf16_f32 %0, %1, %2" : "=v"(r) : "v"(lo), "v"(hi));
    return r;
}

__device__ __forceinline__ s16x8 frag4(unsigned a, unsigned b, unsigned c, unsigned d) {
    int4 t = make_int4((int)a, (int)b, (int)c, (int)d);
    return __builtin_bit_cast(s16x8, t);
}

// ---------------- prep: W (fp32, 3x64x1024) -> wb (bf16, 192x1024), biases -> bb[192]
__global__ __launch_bounds__(256) void prep_kernel(
        const float* __restrict__ Wq, const float* __restrict__ bq,
        const float* __restrict__ Wk, const float* __restrict__ bk,
        const float* __restrict__ Wv, const float* __restrict__ bv,
        unsigned short* __restrict__ wb, float* __restrict__ bb) {
    int gid = blockIdx.x * 256 + threadIdx.x;       // 0 .. 192*1024-1
    int row = gid >> 10, col = gid & 1023;
    const float QS = 1.4426950408889634f / 32.0f;   // log2(e) / sqrt(1024)
    float w;
    if (row < 64)       w = Wq[row * 1024 + col] * QS;
    else if (row < 128) w = Wk[(row - 64) * 1024 + col];
    else                w = Wv[(row - 128) * 1024 + col];
    wb[gid] = f2bf(w);
    if (gid < 192) {
        float b;
        if (gid < 64)       b = bq[gid] * QS;
        else if (gid < 128) b = bk[gid - 64];
        else                b = bv[gid - 128];
        bb[gid] = b;
    }
}

// ---------------- proj: x @ wb^T + bb -> qw, kw (8192x64 bf16), vt2 (tiled V^T)
// vt2 layout: [kv/64][dv(64)][kv%64] -- dense 8KB tile per 64-kv block.
#define XPAD 1040   // shorts per LDS row
__global__ __launch_bounds__(768) void proj_kernel(
        const float* __restrict__ x, const unsigned short* __restrict__ wb,
        const float* __restrict__ bb,
        unsigned short* __restrict__ qw, unsigned short* __restrict__ kw,
        unsigned short* __restrict__ vt2) {
    __shared__ __align__(16) unsigned short xb[16][XPAD];
    int tid = threadIdx.x;
    int row0 = blockIdx.x * 16;

    if (tid < 512) {
        #pragma unroll
        for (int i = 0; i < 8; ++i) {
            int flat = i * 2048 + tid * 4;           // 16x1024 elems
            int r = flat >> 10, col = flat & 1023;
            float4 f = *(const float4*)(x + (size_t)(row0 + r) * EMB + col);
            uint2 p;
            p.x = cvt_pk_bf16(f.x, f.y);
            p.y = cvt_pk_bf16(f.z, f.w);
            *(uint2*)(&xb[r][col]) = p;
        }
    }
    __syncthreads();

    int wave = tid >> 6;            // 0..11 = output col-tile
    int lane = tid & 63;
    int c = lane & 15, g = lane >> 4;

    f32x4 acc = {};
    const unsigned short* bp0 = wb + (size_t)(wave * 16 + c) * EMB;
    #pragma unroll 8
    for (int ks = 0; ks < EMB / 32; ++ks) {
        s16x8 a = *(const s16x8*)(&xb[c][ks * 32 + g * 8]);
        s16x8 b = *(const s16x8*)(bp0 + ks * 32 + g * 8);
        acc = __builtin_amdgcn_mfma_f32_16x16x32_bf16(a, b, acc, 0, 0, 0);
    }
    float bias = bb[wave * 16 + c];
    acc[0] += bias; acc[1] += bias; acc[2] += bias; acc[3] += bias;
    if (wave < 4) {
        int col = wave * 16 + c;
        #pragma unroll
        for (int r = 0; r < 4; ++r)
            qw[(size_t)(row0 + g * 4 + r) * HD + col] = f2bf(acc[r]);
    } else if (wave < 8) {
        int col = (wave - 4) * 16 + c;
        #pragma unroll
        for (int r = 0; r < 4; ++r)
            kw[(size_t)(row0 + g * 4 + r) * HD + col] = f2bf(acc[r]);
    } else {
        int d = (wave - 8) * 16 + c;
        uint2 pack;
        pack.x = cvt_pk_bf16(acc[0], acc[1]);
        pack.y = cvt_pk_bf16(acc[2], acc[3]);
        *(uint2*)(vt2 + (size_t)(row0 >> 6) * 4096 + d * 64 + (row0 & 63) + g * 4) = pack;
    }
}

// ---- attn helpers: __forceinline__ guarantees inlining so SROA promotes all
// arrays (static indices only) into registers. R6's lambdas were NOT inlined
// -> arrays went to scratch -> 200 MB of spill traffic. (rule #19/#20)
__device__ __forceinline__ void load_k_frags(
        s16x8 (&kf)[2][4], const unsigned short* __restrict__ kw,
        int kvi, int c, int g) {
    #pragma unroll
    for (int kh = 0; kh < 2; ++kh)
        #pragma unroll
        for (int t = 0; t < 4; ++t)
            kf[kh][t] = *(const s16x8*)(kw + (size_t)(kvi + t * 16 + c) * HD + kh * 32 + g * 8);
}

__device__ __forceinline__ void attn_body(
        const s16x8 (&kf)[2][4], const s16x8 (&aq)[4][2],
        f32x4 (&o)[4][4], float (&l)[4],
        const unsigned short* __restrict__ vt2, int kvi,
        int c, int g, int moff, bool odd) {
    // V frags for this iter (consumed ~500 cyc later -> L2 latency hidden)
    const unsigned short* vtile = vt2 + (size_t)(kvi >> 6) * 4096;
    s16x8 v0[4], v1[4];
    #pragma unroll
    for (int t = 0; t < 4; ++t) {
        v0[t] = *(const s16x8*)(vtile + (t * 16 + c) * 64 + moff);
        v1[t] = *(const s16x8*)(vtile + (t * 16 + c) * 64 + 32 + moff);
    }
    #pragma unroll
    for (int qp = 0; qp < 2; ++qp) {
        // QK for a pair of q-tiles (st kept to 32 VGPR)
        f32x4 st[2][4] = {};
        #pragma unroll
        for (int kh = 0; kh < 2; ++kh)
            #pragma unroll
            for (int q = 0; q < 2; ++q)
                #pragma unroll
                for (int t = 0; t < 4; ++t)
                    st[q][t] = __builtin_amdgcn_mfma_f32_16x16x32_bf16(
                        kf[kh][t], aq[qp * 2 + q][kh], st[q][t], 0, 0, 0);
        #pragma unroll
        for (int q = 0; q < 2; ++q) {
            int qt = qp * 2 + q;
            float p[4][4];
            #pragma unroll
            for (int t = 0; t < 4; ++t)
                #pragma unroll
                for (int r = 0; r < 4; ++r)
                    p[t][r] = exp2f(st[q][t][r]);
            float s0 = (p[0][0] + p[0][1]) + (p[0][2] + p[0][3]);
            float s1 = (p[1][0] + p[1][1]) + (p[1][2] + p[1][3]);
            float s2 = (p[2][0] + p[2][1]) + (p[2][2] + p[2][3]);
            float s3 = (p[3][0] + p[3][1]) + (p[3][2] + p[3][3]);
            l[qt] += (s0 + s1) + (s2 + s3);
            unsigned W[4][2];
            #pragma unroll
            for (int t = 0; t < 4; ++t) {
                W[t][0] = cvt_pk_bf16(p[t][0], p[t][1]);
                W[t][1] = cvt_pk_bf16(p[t][2], p[t][3]);
            }
            #pragma unroll
            for (int ks = 0; ks < 2; ++ks) {
                unsigned ael = W[2 * ks][0],     aeh = W[2 * ks][1];
                unsigned aol = W[2 * ks + 1][0], aoh = W[2 * ks + 1][1];
                unsigned sl = odd ? ael : aol;   // what partner g^1 needs
                unsigned sh = odd ? aeh : aoh;
                unsigned rl = (unsigned)__builtin_amdgcn_ds_swizzle((int)sl, 0x401F); // lane^16
                unsigned rh = (unsigned)__builtin_amdgcn_ds_swizzle((int)sh, 0x401F);
                unsigned f0 = odd ? rl : ael;
                unsigned f1 = odd ? rh : aeh;
                unsigned f2 = odd ? aol : rl;
                unsigned f3 = odd ? aoh : rh;
                s16x8 pa = frag4(f0, f1, f2, f3);
                #pragma unroll
                for (int t = 0; t < 4; ++t) {
                    s16x8 vb = ks ? v1[t] : v0[t];
                    o[qt][t] = __builtin_amdgcn_mfma_f32_16x16x32_bf16(pa, vb, o[qt][t], 0, 0, 0);
                }
            }
        }
    }
}

// ---------------- attn: swapped-QK flash, no max, no LDS, 64 q-rows per wave,
// register-pipelined K (next-iter K prefetched before current body; one full
// body of compute (~1100 cyc) covers the L2 latency).
template <int S>
__global__ __launch_bounds__(256, 2) void attn_kernel(
        const unsigned short* __restrict__ qw, const unsigned short* __restrict__ kw,
        const unsigned short* __restrict__ vt2,
        float* __restrict__ po, float* __restrict__ pl) {
    constexpr int KVS = TOK / S;
    constexpr int NIT = KVS / KVBLK;     // 8 for S=16 (even: 2x-unrolled pipeline)
    constexpr int QB = TOK / 256;        // 32 qblocks of 256 rows
    int wave = threadIdx.x >> 6;
    int lane = threadIdx.x & 63;
    int c = lane & 15, g = lane >> 4;
    int qb = blockIdx.x % QB;
    int split = blockIdx.x / QB;
    int wq0 = qb * 256 + wave * 64;      // this wave's 64 q-rows
    int kv0 = split * KVS;
    int moff = (((g & 1) << 1) | (g >> 1)) * 8;  // permuted kv chunk within 32
    bool odd = (g & 1) != 0;

    // Q B-frags: 4 q-tiles x 2 k-halves (loop-invariant)
    s16x8 aq[4][2];
    #pragma unroll
    for (int qt = 0; qt < 4; ++qt)
        #pragma unroll
        for (int kh = 0; kh < 2; ++kh)
            aq[qt][kh] = *(const s16x8*)(qw + (size_t)(wq0 + qt * 16 + c) * HD + kh * 32 + g * 8);

    f32x4 o[4][4] = {};
    float l[4] = {};

    // software pipeline: 2x-unrolled, K double-buffered in registers.
    // Final prefetch reads past this split's kv range -- lands in ws (valid
    // memory, vt2 region), never consumed.
    s16x8 kA[2][4], kB[2][4];
    load_k_frags(kA, kw, kv0, c, g);
    #pragma unroll 1
    for (int it2 = 0; it2 < NIT / 2; ++it2) {
        int kviA = kv0 + it2 * 2 * KVBLK;
        int kviB = kviA + KVBLK;
        load_k_frags(kB, kw, kviB, c, g);
        attn_body(kA, aq, o, l, vt2, kviA, c, g, moff, odd);
        load_k_frags(kA, kw, kviB + KVBLK, c, g);
        attn_body(kB, aq, o, l, vt2, kviB, c, g, moff, odd);
    }

    // epilogue: o[qt][t] row = g*4+r (q within tile), col = c (dv within tile t)
    #pragma unroll
    for (int qt = 0; qt < 4; ++qt) {
        #pragma unroll
        for (int t = 0; t < 4; ++t)
            #pragma unroll
            for (int r = 0; r < 4; ++r)
                po[((size_t)split * TOK + wq0 + qt * 16 + g * 4 + r) * HD + t * 16 + c] = o[qt][t][r];
        float v = l[qt];
        v += __shfl_xor(v, 16);
        v += __shfl_xor(v, 32);
        if (g == 0)
            pl[split * TOK + wq0 + qt * 16 + c] = v;
    }
}

// ---------------- combine: sum S splits, divide by total denom, tile x16 heads.
template <int S>
__global__ __launch_bounds__(256) void combine_kernel(
        const float* __restrict__ po, const float* __restrict__ pl,
        float* __restrict__ out) {
    int gid = blockIdx.x * 256 + threadIdx.x;   // 0 .. 8192*16-1
    int row = gid >> 4;
    int dc = (gid & 15) * 4;
    float4 acc = {0.f, 0.f, 0.f, 0.f};
    float denom = 0.f;
    #pragma unroll
    for (int s = 0; s < S; ++s) {
        denom += pl[s * TOK + row];
        float4 p = *(const float4*)(po + ((size_t)s * TOK + row) * HD + dc);
        acc.x += p.x; acc.y += p.y; acc.z += p.z; acc.w += p.w;
    }
    float inv = 1.0f / denom;
    acc.x *= inv; acc.y *= inv; acc.z *= inv; acc.w *= inv;
    #pragma unroll
    for (int h = 0; h < HEADS; ++h)
        *(float4*)(out + (size_t)row * EMB + h * HD + dc) = acc;
}

extern "C" void kernel_launch(void* const* d_in, const int* in_sizes, int n_in,
                              void* d_out, int out_size, void* d_ws, size_t ws_size,
                              hipStream_t stream) {
    const float* x  = (const float*)d_in[0];
    const float* Wq = (const float*)d_in[1];
    const float* bq = (const float*)d_in[2];
    const float* Wk = (const float*)d_in[3];
    const float* bk = (const float*)d_in[4];
    const float* Wv = (const float*)d_in[5];
    const float* bv = (const float*)d_in[6];
    float* out = (float*)d_out;
    char* ws = (char*)d_ws;
    unsigned short* wb  = (unsigned short*)(ws + 0x000000);  // 192x1024 bf16 = 384K
    float*          bb  = (float*)         (ws + 0x060000);  // 192 f32
    unsigned short* qw  = (unsigned short*)(ws + 0x061000);  // 8192x64 bf16 = 1M
    unsigned short* kw  = (unsigned short*)(ws + 0x161000);  // 1M
    unsigned short* vt2 = (unsigned short*)(ws + 0x261000);  // tiled V^T = 1M
    float*          po  = (float*)         (ws + 0x361000);  // S x 8192x64 f32 (2M each)

    prep_kernel<<<dim3(768), dim3(256), 0, stream>>>(Wq, bq, Wk, bk, Wv, bv, wb, bb);
    proj_kernel<<<dim3(512), dim3(768), 0, stream>>>(x, wb, bb, qw, kw, vt2);

    const size_t base = 0x361000;
    const size_t per_split = (size_t)TOK * HD * 4;       // 2 MB po
    const size_t per_pl    = (size_t)TOK * 4;            // 32 KB
    auto need = [&](int s) { return base + (size_t)s * (per_split + per_pl) + 0x100000; };

    if (ws_size >= need(16)) {
        float* pl = (float*)(ws + base + 16 * per_split);
        attn_kernel<16><<<dim3(32 * 16), dim3(256), 0, stream>>>(qw, kw, vt2, po, pl);
        combine_kernel<16><<<dim3(512), dim3(256), 0, stream>>>(po, pl, out);
    } else {
        float* pl = (float*)(ws + base + 8 * per_split);
        attn_kernel<8><<<dim3(32 * 8), dim3(256), 0, stream>>>(qw, kw, vt2, po, pl);
        combine_kernel<8><<<dim3(512), dim3(256), 0, stream>>>(po, pl, out);
    }
}

// Round 8
// 162.622 us; speedup vs baseline: 1.2031x; 1.1773x over previous
//
#include <hip/hip_runtime.h>
#include <stdint.h>

#define TOK 8192      // B*T = 4*2048
#define EMB 1024
#define HD 64         // head_out
#define HEADS 16
#define KVBLK 64

typedef float f32x4 __attribute__((ext_vector_type(4)));
typedef short s16x8 __attribute__((ext_vector_type(8)));

__device__ __forceinline__ unsigned short f2bf(float f) {
    unsigned u = __float_as_uint(f);
    unsigned r = (u + 0x7FFFu + ((u >> 16) & 1u)) >> 16;  // RNE
    return (unsigned short)r;
}

__device__ __forceinline__ unsigned cvt_pk_bf16(float lo, float hi) {
    unsigned r;
    asm("v_cvt_pk_bf16_f32 %0, %1, %2" : "=v"(r) : "v"(lo), "v"(hi));
    return r;
}

__device__ __forceinline__ s16x8 frag4(unsigned a, unsigned b, unsigned c, unsigned d) {
    int4 t = make_int4((int)a, (int)b, (int)c, (int)d);
    return __builtin_bit_cast(s16x8, t);
}

// ---------------- prep: W (fp32, 3x64x1024) -> wb (bf16, 192x1024), biases -> bb[192]
__global__ __launch_bounds__(256) void prep_kernel(
        const float* __restrict__ Wq, const float* __restrict__ bq,
        const float* __restrict__ Wk, const float* __restrict__ bk,
        const float* __restrict__ Wv, const float* __restrict__ bv,
        unsigned short* __restrict__ wb, float* __restrict__ bb) {
    int gid = blockIdx.x * 256 + threadIdx.x;       // 0 .. 192*1024-1
    int row = gid >> 10, col = gid & 1023;
    const float QS = 1.4426950408889634f / 32.0f;   // log2(e) / sqrt(1024)
    float w;
    if (row < 64)       w = Wq[row * 1024 + col] * QS;
    else if (row < 128) w = Wk[(row - 64) * 1024 + col];
    else                w = Wv[(row - 128) * 1024 + col];
    wb[gid] = f2bf(w);
    if (gid < 192) {
        float b;
        if (gid < 64)       b = bq[gid] * QS;
        else if (gid < 128) b = bk[gid - 64];
        else                b = bv[gid - 128];
        bb[gid] = b;
    }
}

// ---------------- proj: x @ wb^T + bb -> qw (linear 8192x64 bf16), and K/V as
// fragment-ordered per-64kv-tile images (8KB each) so attn's ds_read_b128 is
// base + lane*16 (conflict-free) and gload_lds staging is a linear 8KB copy.
// K image: tile*8192 + (kh*4+t)*1024 + (g*16+c)*16 + j*2  holds K[t*16+c][kh*32+g*8+j]
// V image: tile*8192 + (ks*4+t)*1024 + (g*16+c)*16 + j*2  holds Vt[t*16+c][ks*32+perm(g)*8+j]
//   (perm = [0,2,1,3], an involution; matches attn's moff redistribution trick)
#define XPAD 1040   // shorts per LDS row
__global__ __launch_bounds__(768) void proj_kernel(
        const float* __restrict__ x, const unsigned short* __restrict__ wb,
        const float* __restrict__ bb,
        unsigned short* __restrict__ qw, unsigned char* __restrict__ kimg,
        unsigned char* __restrict__ vimg) {
    __shared__ __align__(16) unsigned short xb[16][XPAD];
    int tid = threadIdx.x;
    int row0 = blockIdx.x * 16;

    if (tid < 512) {
        #pragma unroll
        for (int i = 0; i < 8; ++i) {
            int flat = i * 2048 + tid * 4;           // 16x1024 elems
            int r = flat >> 10, col = flat & 1023;
            float4 f = *(const float4*)(x + (size_t)(row0 + r) * EMB + col);
            uint2 p;
            p.x = cvt_pk_bf16(f.x, f.y);
            p.y = cvt_pk_bf16(f.z, f.w);
            *(uint2*)(&xb[r][col]) = p;
        }
    }
    __syncthreads();

    int wave = tid >> 6;            // 0..11 = output col-tile
    int lane = tid & 63;
    int c = lane & 15, g = lane >> 4;

    f32x4 acc = {};
    const unsigned short* bp0 = wb + (size_t)(wave * 16 + c) * EMB;
    #pragma unroll 8
    for (int ks = 0; ks < EMB / 32; ++ks) {
        s16x8 a = *(const s16x8*)(&xb[c][ks * 32 + g * 8]);
        s16x8 b = *(const s16x8*)(bp0 + ks * 32 + g * 8);
        acc = __builtin_amdgcn_mfma_f32_16x16x32_bf16(a, b, acc, 0, 0, 0);
    }
    float bias = bb[wave * 16 + c];
    acc[0] += bias; acc[1] += bias; acc[2] += bias; acc[3] += bias;

    size_t tile = (size_t)(row0 >> 6);
    int tI = (row0 >> 4) & 3;       // which 16-row sub-tile of the 64-kv tile

    if (wave < 4) {
        int col = wave * 16 + c;
        #pragma unroll
        for (int r = 0; r < 4; ++r)
            qw[(size_t)(row0 + g * 4 + r) * HD + col] = f2bf(acc[r]);
    } else if (wave < 8) {
        // K rows row0+g*4+r, col C = (wave-4)*16+c
        int wv = wave - 4;
        int C = wv * 16 + c;
        int kh = C >> 5;
        int gg = (C & 31) >> 3;
        int j = C & 7;
        unsigned char* base = kimg + tile * 8192 + (size_t)((kh * 4 + tI) * 1024 + j * 2);
        #pragma unroll
        for (int r = 0; r < 4; ++r) {
            int cl = g * 4 + r;                    // row's c-slot within sub-tile
            *(unsigned short*)(base + (gg * 16 + cl) * 16) = f2bf(acc[r]);
        }
    } else {
        // V: d = (wave-8)*16+c, kv tokens row0+g*4+0..3
        int t = wave - 8;
        int base16 = tI * 16 + g * 4;              // kv&63 base, multiple of 4
        int ks = base16 >> 5;
        int s = (base16 >> 3) & 3;
        int gg = ((s & 1) << 1) | (s >> 1);        // perm (involution)
        int j0 = base16 & 7;                       // 0 or 4
        uint2 pack;
        pack.x = cvt_pk_bf16(acc[0], acc[1]);
        pack.y = cvt_pk_bf16(acc[2], acc[3]);
        *(uint2*)(vimg + tile * 8192 +
                  (size_t)((ks * 4 + t) * 1024 + (gg * 16 + c) * 16 + j0 * 2)) = pack;
    }
}

// ---------------- attn: swapped-QK flash, no max, 64 q-rows/wave, K/V staged
// block-wide into double-buffered LDS via global_load_lds (fragment-ordered
// images -> linear conflict-free ds_read_b128; zero VGPR staging cost).
template <int S>
__global__ __launch_bounds__(256, 2) void attn_kernel(
        const unsigned short* __restrict__ qw, const unsigned char* __restrict__ kimg,
        const unsigned char* __restrict__ vimg,
        float* __restrict__ po, float* __restrict__ pl) {
    constexpr int KVS = TOK / S;
    constexpr int NIT = KVS / KVBLK;     // 8 for S=16
    constexpr int QB = TOK / 256;        // 32 qblocks of 256 rows
    __shared__ __align__(16) unsigned char lds[2][16384];  // [buf][K 8KB | V 8KB]
    int wave = threadIdx.x >> 6;
    int lane = threadIdx.x & 63;
    int c = lane & 15, g = lane >> 4;
    int qb = blockIdx.x % QB;
    int split = blockIdx.x / QB;
    int wq0 = qb * 256 + wave * 64;      // this wave's 64 q-rows
    int tile0 = split * NIT;             // first 64-kv tile of this split
    bool odd = (g & 1) != 0;

    // Q B-frags: 4 q-tiles x 2 k-halves (loop-invariant)
    s16x8 aq[4][2];
    #pragma unroll
    for (int qt = 0; qt < 4; ++qt)
        #pragma unroll
        for (int kh = 0; kh < 2; ++kh)
            aq[qt][kh] = *(const s16x8*)(qw + (size_t)(wq0 + qt * 16 + c) * HD + kh * 32 + g * 8);

    f32x4 o[4][4] = {};
    float l[4] = {};

    // ---- staging: wave w copies 2KB of K image + 2KB of V image per tile.
    auto stage = [&](int buf, int tile) {
        const unsigned char* kg = kimg + (size_t)tile * 8192;
        const unsigned char* vg = vimg + (size_t)tile * 8192;
        #pragma unroll
        for (int j = 0; j < 2; ++j) {
            int off = (j * 4 + wave) * 1024;
            __builtin_amdgcn_global_load_lds(
                (const __attribute__((address_space(1))) void*)(kg + off + lane * 16),
                (__attribute__((address_space(3))) void*)(&lds[buf][off]), 16, 0, 0);
            __builtin_amdgcn_global_load_lds(
                (const __attribute__((address_space(1))) void*)(vg + off + lane * 16),
                (__attribute__((address_space(3))) void*)(&lds[buf][8192 + off]), 16, 0, 0);
        }
    };

    stage(0, tile0);
    __syncthreads();     // drains vmcnt (compiler emits vmcnt(0) before barrier)

    int buf = 0;
    #pragma unroll 1
    for (int it = 0; it < NIT; ++it) {
        int nt = (it + 1 < NIT) ? it + 1 : it;   // clamp: last prefetch harmless
        stage(buf ^ 1, tile0 + nt);

        const unsigned char* Kl = &lds[buf][0];
        const unsigned char* Vl = &lds[buf][8192];

        // K frags once per iter, shared by all 4 q-tiles (linear reads)
        s16x8 kf[2][4];
        #pragma unroll
        for (int kh = 0; kh < 2; ++kh)
            #pragma unroll
            for (int t = 0; t < 4; ++t)
                kf[kh][t] = *(const s16x8*)(Kl + (kh * 4 + t) * 1024 + lane * 16);

        // phase 1: QK + exp2 + pack for all 4 q-tiles
        unsigned Wall[4][8];
        #pragma unroll
        for (int qp = 0; qp < 2; ++qp) {
            f32x4 st[2][4] = {};
            #pragma unroll
            for (int kh = 0; kh < 2; ++kh)
                #pragma unroll
                for (int q = 0; q < 2; ++q)
                    #pragma unroll
                    for (int t = 0; t < 4; ++t)
                        st[q][t] = __builtin_amdgcn_mfma_f32_16x16x32_bf16(
                            kf[kh][t], aq[qp * 2 + q][kh], st[q][t], 0, 0, 0);
            #pragma unroll
            for (int q = 0; q < 2; ++q) {
                int qt = qp * 2 + q;
                float p[4][4];
                #pragma unroll
                for (int t = 0; t < 4; ++t)
                    #pragma unroll
                    for (int r = 0; r < 4; ++r)
                        p[t][r] = exp2f(st[q][t][r]);
                float s0 = (p[0][0] + p[0][1]) + (p[0][2] + p[0][3]);
                float s1 = (p[1][0] + p[1][1]) + (p[1][2] + p[1][3]);
                float s2 = (p[2][0] + p[2][1]) + (p[2][2] + p[2][3]);
                float s3 = (p[3][0] + p[3][1]) + (p[3][2] + p[3][3]);
                l[qt] += (s0 + s1) + (s2 + s3);
                #pragma unroll
                for (int t = 0; t < 4; ++t) {
                    Wall[qt][t * 2 + 0] = cvt_pk_bf16(p[t][0], p[t][1]);
                    Wall[qt][t * 2 + 1] = cvt_pk_bf16(p[t][2], p[t][3]);
                }
            }
        }

        // phase 2: PV (V frags linear from LDS, shared across q-tiles)
        #pragma unroll
        for (int ks = 0; ks < 2; ++ks) {
            s16x8 vf[4];
            #pragma unroll
            for (int t = 0; t < 4; ++t)
                vf[t] = *(const s16x8*)(Vl + (ks * 4 + t) * 1024 + lane * 16);
            #pragma unroll
            for (int qt = 0; qt < 4; ++qt) {
                unsigned ael = Wall[qt][4 * ks + 0], aeh = Wall[qt][4 * ks + 1];
                unsigned aol = Wall[qt][4 * ks + 2], aoh = Wall[qt][4 * ks + 3];
                unsigned sl = odd ? ael : aol;   // what partner g^1 needs
                unsigned sh = odd ? aeh : aoh;
                unsigned rl = (unsigned)__builtin_amdgcn_ds_swizzle((int)sl, 0x401F); // lane^16
                unsigned rh = (unsigned)__builtin_amdgcn_ds_swizzle((int)sh, 0x401F);
                unsigned f0 = odd ? rl : ael;
                unsigned f1 = odd ? rh : aeh;
                unsigned f2 = odd ? aol : rl;
                unsigned f3 = odd ? aoh : rh;
                s16x8 pa = frag4(f0, f1, f2, f3);
                #pragma unroll
                for (int t = 0; t < 4; ++t)
                    o[qt][t] = __builtin_amdgcn_mfma_f32_16x16x32_bf16(pa, vf[t], o[qt][t], 0, 0, 0);
            }
        }
        __syncthreads();
        buf ^= 1;
    }

    // epilogue: o[qt][t] row = g*4+r (q within tile), col = c (dv within tile t)
    #pragma unroll
    for (int qt = 0; qt < 4; ++qt) {
        #pragma unroll
        for (int t = 0; t < 4; ++t)
            #pragma unroll
            for (int r = 0; r < 4; ++r)
                po[((size_t)split * TOK + wq0 + qt * 16 + g * 4 + r) * HD + t * 16 + c] = o[qt][t][r];
        float v = l[qt];
        v += __shfl_xor(v, 16);
        v += __shfl_xor(v, 32);
        if (g == 0)
            pl[split * TOK + wq0 + qt * 16 + c] = v;
    }
}

// ---------------- combine: sum S splits, divide by total denom, tile x16 heads.
template <int S>
__global__ __launch_bounds__(256) void combine_kernel(
        const float* __restrict__ po, const float* __restrict__ pl,
        float* __restrict__ out) {
    int gid = blockIdx.x * 256 + threadIdx.x;   // 0 .. 8192*16-1
    int row = gid >> 4;
    int dc = (gid & 15) * 4;
    float4 acc = {0.f, 0.f, 0.f, 0.f};
    float denom = 0.f;
    #pragma unroll
    for (int s = 0; s < S; ++s) {
        denom += pl[s * TOK + row];
        float4 p = *(const float4*)(po + ((size_t)s * TOK + row) * HD + dc);
        acc.x += p.x; acc.y += p.y; acc.z += p.z; acc.w += p.w;
    }
    float inv = 1.0f / denom;
    acc.x *= inv; acc.y *= inv; acc.z *= inv; acc.w *= inv;
    #pragma unroll
    for (int h = 0; h < HEADS; ++h)
        *(float4*)(out + (size_t)row * EMB + h * HD + dc) = acc;
}

extern "C" void kernel_launch(void* const* d_in, const int* in_sizes, int n_in,
                              void* d_out, int out_size, void* d_ws, size_t ws_size,
                              hipStream_t stream) {
    const float* x  = (const float*)d_in[0];
    const float* Wq = (const float*)d_in[1];
    const float* bq = (const float*)d_in[2];
    const float* Wk = (const float*)d_in[3];
    const float* bk = (const float*)d_in[4];
    const float* Wv = (const float*)d_in[5];
    const float* bv = (const float*)d_in[6];
    float* out = (float*)d_out;
    char* ws = (char*)d_ws;
    unsigned short* wb   = (unsigned short*)(ws + 0x000000);  // 192x1024 bf16 = 384K
    float*          bb   = (float*)         (ws + 0x060000);  // 192 f32
    unsigned short* qw   = (unsigned short*)(ws + 0x061000);  // 8192x64 bf16 = 1M
    unsigned char*  kimg = (unsigned char*) (ws + 0x161000);  // 128 tiles x 8KB = 1M
    unsigned char*  vimg = (unsigned char*) (ws + 0x261000);  // 1M
    float*          po   = (float*)         (ws + 0x361000);  // S x 8192x64 f32 (2M each)

    prep_kernel<<<dim3(768), dim3(256), 0, stream>>>(Wq, bq, Wk, bk, Wv, bv, wb, bb);
    proj_kernel<<<dim3(512), dim3(768), 0, stream>>>(x, wb, bb, qw, kimg, vimg);

    const size_t base = 0x361000;
    const size_t per_split = (size_t)TOK * HD * 4;       // 2 MB po
    const size_t per_pl    = (size_t)TOK * 4;            // 32 KB
    auto need = [&](int s) { return base + (size_t)s * (per_split + per_pl); };

    if (ws_size >= need(16)) {
        float* pl = (float*)(ws + base + 16 * per_split);
        attn_kernel<16><<<dim3(32 * 16), dim3(256), 0, stream>>>(qw, kimg, vimg, po, pl);
        combine_kernel<16><<<dim3(512), dim3(256), 0, stream>>>(po, pl, out);
    } else {
        float* pl = (float*)(ws + base + 8 * per_split);
        attn_kernel<8><<<dim3(32 * 8), dim3(256), 0, stream>>>(qw, kimg, vimg, po, pl);
        combine_kernel<8><<<dim3(512), dim3(256), 0, stream>>>(po, pl, out);
    }
}

// Round 9
// 151.165 us; speedup vs baseline: 1.2943x; 1.0758x over previous
//
#include <hip/hip_runtime.h>
#include <stdint.h>

#define TOK 8192      // B*T = 4*2048
#define EMB 1024
#define HD 64         // head_out
#define HEADS 16
#define KVBLK 64

typedef float f32x4 __attribute__((ext_vector_type(4)));
typedef short s16x8 __attribute__((ext_vector_type(8)));

__device__ __forceinline__ unsigned short f2bf(float f) {
    unsigned u = __float_as_uint(f);
    unsigned r = (u + 0x7FFFu + ((u >> 16) & 1u)) >> 16;  // RNE
    return (unsigned short)r;
}

__device__ __forceinline__ unsigned cvt_pk_bf16(float lo, float hi) {
    unsigned r;
    asm("v_cvt_pk_bf16_f32 %0, %1, %2" : "=v"(r) : "v"(lo), "v"(hi));
    return r;
}

__device__ __forceinline__ s16x8 frag4(unsigned a, unsigned b, unsigned c, unsigned d) {
    int4 t = make_int4((int)a, (int)b, (int)c, (int)d);
    return __builtin_bit_cast(s16x8, t);
}

// ---------------- prep: W (fp32, 3x64x1024) -> wb (bf16, 192x1024), biases -> bb[192]
__global__ __launch_bounds__(256) void prep_kernel(
        const float* __restrict__ Wq, const float* __restrict__ bq,
        const float* __restrict__ Wk, const float* __restrict__ bk,
        const float* __restrict__ Wv, const float* __restrict__ bv,
        unsigned short* __restrict__ wb, float* __restrict__ bb) {
    int gid = blockIdx.x * 256 + threadIdx.x;       // 0 .. 192*1024-1
    int row = gid >> 10, col = gid & 1023;
    const float QS = 1.4426950408889634f / 32.0f;   // log2(e) / sqrt(1024)
    float w;
    if (row < 64)       w = Wq[row * 1024 + col] * QS;
    else if (row < 128) w = Wk[(row - 64) * 1024 + col];
    else                w = Wv[(row - 128) * 1024 + col];
    wb[gid] = f2bf(w);
    if (gid < 192) {
        float b;
        if (gid < 64)       b = bq[gid] * QS;
        else if (gid < 128) b = bk[gid - 64];
        else                b = bv[gid - 128];
        bb[gid] = b;
    }
}

// ---------------- proj: x @ wb^T + bb -> qw (linear 8192x64 bf16), and K/V as
// fragment-ordered per-64kv-tile images (8KB each) so attn's ds_read_b128 is
// base + lane*16 (conflict-free) and gload_lds staging is a linear 8KB copy.
// K image: tile*8192 + (kh*4+t)*1024 + (g*16+c)*16 + j*2  holds K[t*16+c][kh*32+g*8+j]
// V image: tile*8192 + (ks*4+t)*1024 + (g*16+c)*16 + j*2  holds Vt[t*16+c][ks*32+perm(g)*8+j]
//   (perm = [0,2,1,3], an involution; matches attn's redistribution trick)
#define XPAD 1040   // shorts per LDS row
__global__ __launch_bounds__(768) void proj_kernel(
        const float* __restrict__ x, const unsigned short* __restrict__ wb,
        const float* __restrict__ bb,
        unsigned short* __restrict__ qw, unsigned char* __restrict__ kimg,
        unsigned char* __restrict__ vimg) {
    __shared__ __align__(16) unsigned short xb[16][XPAD];
    int tid = threadIdx.x;
    int row0 = blockIdx.x * 16;

    if (tid < 512) {
        #pragma unroll
        for (int i = 0; i < 8; ++i) {
            int flat = i * 2048 + tid * 4;           // 16x1024 elems
            int r = flat >> 10, col = flat & 1023;
            float4 f = *(const float4*)(x + (size_t)(row0 + r) * EMB + col);
            uint2 p;
            p.x = cvt_pk_bf16(f.x, f.y);
            p.y = cvt_pk_bf16(f.z, f.w);
            *(uint2*)(&xb[r][col]) = p;
        }
    }
    __syncthreads();

    int wave = tid >> 6;            // 0..11 = output col-tile
    int lane = tid & 63;
    int c = lane & 15, g = lane >> 4;

    // two independent accumulator chains (halves the serial MFMA latency chain)
    f32x4 acc0 = {}, acc1 = {};
    const unsigned short* bp0 = wb + (size_t)(wave * 16 + c) * EMB;
    #pragma unroll 8
    for (int ks = 0; ks < 16; ++ks) {
        s16x8 a0 = *(const s16x8*)(&xb[c][ks * 32 + g * 8]);
        s16x8 b0 = *(const s16x8*)(bp0 + ks * 32 + g * 8);
        acc0 = __builtin_amdgcn_mfma_f32_16x16x32_bf16(a0, b0, acc0, 0, 0, 0);
        s16x8 a1 = *(const s16x8*)(&xb[c][(ks + 16) * 32 + g * 8]);
        s16x8 b1 = *(const s16x8*)(bp0 + (ks + 16) * 32 + g * 8);
        acc1 = __builtin_amdgcn_mfma_f32_16x16x32_bf16(a1, b1, acc1, 0, 0, 0);
    }
    float bias = bb[wave * 16 + c];
    f32x4 acc;
    acc[0] = acc0[0] + acc1[0] + bias;
    acc[1] = acc0[1] + acc1[1] + bias;
    acc[2] = acc0[2] + acc1[2] + bias;
    acc[3] = acc0[3] + acc1[3] + bias;

    size_t tile = (size_t)(row0 >> 6);
    int tI = (row0 >> 4) & 3;       // which 16-row sub-tile of the 64-kv tile

    if (wave < 4) {
        int col = wave * 16 + c;
        #pragma unroll
        for (int r = 0; r < 4; ++r)
            qw[(size_t)(row0 + g * 4 + r) * HD + col] = f2bf(acc[r]);
    } else if (wave < 8) {
        // K rows row0+g*4+r, col C = (wave-4)*16+c
        int wv = wave - 4;
        int C = wv * 16 + c;
        int kh = C >> 5;
        int gg = (C & 31) >> 3;
        int j = C & 7;
        unsigned char* base = kimg + tile * 8192 + (size_t)((kh * 4 + tI) * 1024 + j * 2);
        #pragma unroll
        for (int r = 0; r < 4; ++r) {
            int cl = g * 4 + r;                    // row's c-slot within sub-tile
            *(unsigned short*)(base + (gg * 16 + cl) * 16) = f2bf(acc[r]);
        }
    } else {
        // V: d = (wave-8)*16+c, kv tokens row0+g*4+0..3
        int t = wave - 8;
        int base16 = tI * 16 + g * 4;              // kv&63 base, multiple of 4
        int ks = base16 >> 5;
        int s = (base16 >> 3) & 3;
        int gg = ((s & 1) << 1) | (s >> 1);        // perm (involution)
        int j0 = base16 & 7;                       // 0 or 4
        uint2 pack;
        pack.x = cvt_pk_bf16(acc[0], acc[1]);
        pack.y = cvt_pk_bf16(acc[2], acc[3]);
        *(uint2*)(vimg + tile * 8192 +
                  (size_t)((ks * 4 + t) * 1024 + (gg * 16 + c) * 16 + j0 * 2)) = pack;
    }
}

// ---------------- attn: swapped-QK flash, no max, 2 q-tiles (32 rows) per wave.
// Block = 4 waves = 128 q-rows x one kv split; K/V staged block-wide into
// double-buffered LDS via global_load_lds. Smaller per-wave state (~150 regs)
// -> 3 blocks/CU resident (launch_bounds(256,3)): 3 phase-offset barrier groups
// overlap exp2/MFMA/staging across blocks.
template <int S>
__global__ __launch_bounds__(256, 3) void attn_kernel(
        const unsigned short* __restrict__ qw, const unsigned char* __restrict__ kimg,
        const unsigned char* __restrict__ vimg,
        float* __restrict__ po, float* __restrict__ pl) {
    constexpr int KVS = TOK / S;
    constexpr int NIT = KVS / KVBLK;     // 8 for S=16
    constexpr int QB = TOK / 128;        // 64 qblocks of 128 rows
    __shared__ __align__(16) unsigned char lds[2][16384];  // [buf][K 8KB | V 8KB]
    int wave = threadIdx.x >> 6;
    int lane = threadIdx.x & 63;
    int c = lane & 15, g = lane >> 4;
    int qb = blockIdx.x % QB;
    int split = blockIdx.x / QB;
    int wq0 = qb * 128 + wave * 32;      // this wave's 32 q-rows
    int tile0 = split * NIT;             // first 64-kv tile of this split
    bool odd = (g & 1) != 0;

    // Q B-frags: 2 q-tiles x 2 k-halves (loop-invariant)
    s16x8 aq[2][2];
    #pragma unroll
    for (int qt = 0; qt < 2; ++qt)
        #pragma unroll
        for (int kh = 0; kh < 2; ++kh)
            aq[qt][kh] = *(const s16x8*)(qw + (size_t)(wq0 + qt * 16 + c) * HD + kh * 32 + g * 8);

    f32x4 o[2][4] = {};
    float l[2] = {};

    // ---- staging: wave w copies 2KB of K image + 2KB of V image per tile.
    auto stage = [&](int buf, int tile) {
        const unsigned char* kg = kimg + (size_t)tile * 8192;
        const unsigned char* vg = vimg + (size_t)tile * 8192;
        #pragma unroll
        for (int j = 0; j < 2; ++j) {
            int off = (j * 4 + wave) * 1024;
            __builtin_amdgcn_global_load_lds(
                (const __attribute__((address_space(1))) void*)(kg + off + lane * 16),
                (__attribute__((address_space(3))) void*)(&lds[buf][off]), 16, 0, 0);
            __builtin_amdgcn_global_load_lds(
                (const __attribute__((address_space(1))) void*)(vg + off + lane * 16),
                (__attribute__((address_space(3))) void*)(&lds[buf][8192 + off]), 16, 0, 0);
        }
    };

    stage(0, tile0);
    __syncthreads();     // drains vmcnt (compiler emits vmcnt(0) before barrier)

    int buf = 0;
    #pragma unroll 1
    for (int it = 0; it < NIT; ++it) {
        int nt = (it + 1 < NIT) ? it + 1 : it;   // clamp: last prefetch harmless
        stage(buf ^ 1, tile0 + nt);

        const unsigned char* Kl = &lds[buf][0];
        const unsigned char* Vl = &lds[buf][8192];

        // K frags once per iter, shared by both q-tiles (linear reads)
        s16x8 kf[2][4];
        #pragma unroll
        for (int kh = 0; kh < 2; ++kh)
            #pragma unroll
            for (int t = 0; t < 4; ++t)
                kf[kh][t] = *(const s16x8*)(Kl + (kh * 4 + t) * 1024 + lane * 16);

        // phase 1: QK + exp2 + pack for both q-tiles
        f32x4 st[2][4] = {};
        #pragma unroll
        for (int kh = 0; kh < 2; ++kh)
            #pragma unroll
            for (int q = 0; q < 2; ++q)
                #pragma unroll
                for (int t = 0; t < 4; ++t)
                    st[q][t] = __builtin_amdgcn_mfma_f32_16x16x32_bf16(
                        kf[kh][t], aq[q][kh], st[q][t], 0, 0, 0);

        unsigned Wall[2][8];
        #pragma unroll
        for (int q = 0; q < 2; ++q) {
            float p[4][4];
            #pragma unroll
            for (int t = 0; t < 4; ++t)
                #pragma unroll
                for (int r = 0; r < 4; ++r)
                    p[t][r] = exp2f(st[q][t][r]);
            float s0 = (p[0][0] + p[0][1]) + (p[0][2] + p[0][3]);
            float s1 = (p[1][0] + p[1][1]) + (p[1][2] + p[1][3]);
            float s2 = (p[2][0] + p[2][1]) + (p[2][2] + p[2][3]);
            float s3 = (p[3][0] + p[3][1]) + (p[3][2] + p[3][3]);
            l[q] += (s0 + s1) + (s2 + s3);
            #pragma unroll
            for (int t = 0; t < 4; ++t) {
                Wall[q][t * 2 + 0] = cvt_pk_bf16(p[t][0], p[t][1]);
                Wall[q][t * 2 + 1] = cvt_pk_bf16(p[t][2], p[t][3]);
            }
        }

        // phase 2: PV (V frags linear from LDS, shared across q-tiles)
        #pragma unroll
        for (int ks = 0; ks < 2; ++ks) {
            s16x8 vf[4];
            #pragma unroll
            for (int t = 0; t < 4; ++t)
                vf[t] = *(const s16x8*)(Vl + (ks * 4 + t) * 1024 + lane * 16);
            #pragma unroll
            for (int qt = 0; qt < 2; ++qt) {
                unsigned ael = Wall[qt][4 * ks + 0], aeh = Wall[qt][4 * ks + 1];
                unsigned aol = Wall[qt][4 * ks + 2], aoh = Wall[qt][4 * ks + 3];
                unsigned sl = odd ? ael : aol;   // what partner g^1 needs
                unsigned sh = odd ? aeh : aoh;
                unsigned rl = (unsigned)__builtin_amdgcn_ds_swizzle((int)sl, 0x401F); // lane^16
                unsigned rh = (unsigned)__builtin_amdgcn_ds_swizzle((int)sh, 0x401F);
                unsigned f0 = odd ? rl : ael;
                unsigned f1 = odd ? rh : aeh;
                unsigned f2 = odd ? aol : rl;
                unsigned f3 = odd ? aoh : rh;
                s16x8 pa = frag4(f0, f1, f2, f3);
                #pragma unroll
                for (int t = 0; t < 4; ++t)
                    o[qt][t] = __builtin_amdgcn_mfma_f32_16x16x32_bf16(pa, vf[t], o[qt][t], 0, 0, 0);
            }
        }
        __syncthreads();
        buf ^= 1;
    }

    // epilogue: o[qt][t] row = g*4+r (q within tile), col = c (dv within tile t)
    #pragma unroll
    for (int qt = 0; qt < 2; ++qt) {
        #pragma unroll
        for (int t = 0; t < 4; ++t)
            #pragma unroll
            for (int r = 0; r < 4; ++r)
                po[((size_t)split * TOK + wq0 + qt * 16 + g * 4 + r) * HD + t * 16 + c] = o[qt][t][r];
        float v = l[qt];
        v += __shfl_xor(v, 16);
        v += __shfl_xor(v, 32);
        if (g == 0)
            pl[split * TOK + wq0 + qt * 16 + c] = v;
    }
}

// ---------------- combine: sum S splits, divide by total denom, tile x16 heads.
template <int S>
__global__ __launch_bounds__(256) void combine_kernel(
        const float* __restrict__ po, const float* __restrict__ pl,
        float* __restrict__ out) {
    int gid = blockIdx.x * 256 + threadIdx.x;   // 0 .. 8192*16-1
    int row = gid >> 4;
    int dc = (gid & 15) * 4;
    float4 acc = {0.f, 0.f, 0.f, 0.f};
    float denom = 0.f;
    #pragma unroll
    for (int s = 0; s < S; ++s) {
        denom += pl[s * TOK + row];
        float4 p = *(const float4*)(po + ((size_t)s * TOK + row) * HD + dc);
        acc.x += p.x; acc.y += p.y; acc.z += p.z; acc.w += p.w;
    }
    float inv = 1.0f / denom;
    acc.x *= inv; acc.y *= inv; acc.z *= inv; acc.w *= inv;
    #pragma unroll
    for (int h = 0; h < HEADS; ++h)
        *(float4*)(out + (size_t)row * EMB + h * HD + dc) = acc;
}

extern "C" void kernel_launch(void* const* d_in, const int* in_sizes, int n_in,
                              void* d_out, int out_size, void* d_ws, size_t ws_size,
                              hipStream_t stream) {
    const float* x  = (const float*)d_in[0];
    const float* Wq = (const float*)d_in[1];
    const float* bq = (const float*)d_in[2];
    const float* Wk = (const float*)d_in[3];
    const float* bk = (const float*)d_in[4];
    const float* Wv = (const float*)d_in[5];
    const float* bv = (const float*)d_in[6];
    float* out = (float*)d_out;
    char* ws = (char*)d_ws;
    unsigned short* wb   = (unsigned short*)(ws + 0x000000);  // 192x1024 bf16 = 384K
    float*          bb   = (float*)         (ws + 0x060000);  // 192 f32
    unsigned short* qw   = (unsigned short*)(ws + 0x061000);  // 8192x64 bf16 = 1M
    unsigned char*  kimg = (unsigned char*) (ws + 0x161000);  // 128 tiles x 8KB = 1M
    unsigned char*  vimg = (unsigned char*) (ws + 0x261000);  // 1M
    float*          po   = (float*)         (ws + 0x361000);  // S x 8192x64 f32 (2M each)

    prep_kernel<<<dim3(768), dim3(256), 0, stream>>>(Wq, bq, Wk, bk, Wv, bv, wb, bb);
    proj_kernel<<<dim3(512), dim3(768), 0, stream>>>(x, wb, bb, qw, kimg, vimg);

    const size_t base = 0x361000;
    const size_t per_split = (size_t)TOK * HD * 4;       // 2 MB po
    const size_t per_pl    = (size_t)TOK * 4;            // 32 KB
    auto need = [&](int s) { return base + (size_t)s * (per_split + per_pl); };

    if (ws_size >= need(16)) {
        float* pl = (float*)(ws + base + 16 * per_split);
        attn_kernel<16><<<dim3(64 * 16), dim3(256), 0, stream>>>(qw, kimg, vimg, po, pl);
        combine_kernel<16><<<dim3(512), dim3(256), 0, stream>>>(po, pl, out);
    } else {
        float* pl = (float*)(ws + base + 8 * per_split);
        attn_kernel<8><<<dim3(64 * 8), dim3(256), 0, stream>>>(qw, kimg, vimg, po, pl);
        combine_kernel<8><<<dim3(512), dim3(256), 0, stream>>>(po, pl, out);
    }
}

// Round 11
// 144.690 us; speedup vs baseline: 1.3522x; 1.0447x over previous
//
#include <hip/hip_runtime.h>
#include <stdint.h>

#define TOK 8192      // B*T = 4*2048
#define EMB 1024
#define HD 64         // head_out
#define HEADS 16

typedef float f32x4 __attribute__((ext_vector_type(4)));
typedef short s16x8 __attribute__((ext_vector_type(8)));

__device__ __forceinline__ unsigned short f2bf(float f) {
    unsigned u = __float_as_uint(f);
    unsigned r = (u + 0x7FFFu + ((u >> 16) & 1u)) >> 16;  // RNE
    return (unsigned short)r;
}

__device__ __forceinline__ unsigned cvt_pk_bf16(float lo, float hi) {
    unsigned r;
    asm("v_cvt_pk_bf16_f32 %0, %1, %2" : "=v"(r) : "v"(lo), "v"(hi));
    return r;
}

__device__ __forceinline__ s16x8 frag4(unsigned a, unsigned b, unsigned c, unsigned d) {
    int4 t = make_int4((int)a, (int)b, (int)c, (int)d);
    return __builtin_bit_cast(s16x8, t);
}

// ---------------- prep: W (fp32, 3x64x1024) -> wb (bf16, 192x1024), biases -> bb[192]
__global__ __launch_bounds__(256) void prep_kernel(
        const float* __restrict__ Wq, const float* __restrict__ bq,
        const float* __restrict__ Wk, const float* __restrict__ bk,
        const float* __restrict__ Wv, const float* __restrict__ bv,
        unsigned short* __restrict__ wb, float* __restrict__ bb) {
    int gid = blockIdx.x * 256 + threadIdx.x;       // 0 .. 192*1024-1
    int row = gid >> 10, col = gid & 1023;
    const float QS = 1.4426950408889634f / 32.0f;   // log2(e) / sqrt(1024)
    float w;
    if (row < 64)       w = Wq[row * 1024 + col] * QS;
    else if (row < 128) w = Wk[(row - 64) * 1024 + col];
    else                w = Wv[(row - 128) * 1024 + col];
    wb[gid] = f2bf(w);
    if (gid < 192) {
        float b;
        if (gid < 64)       b = bq[gid] * QS;
        else if (gid < 128) b = bk[gid - 64];
        else                b = bv[gid - 128];
        bb[gid] = b;
    }
}

// ---------------- proj: x @ wb^T + bb -> qw (linear 8192x64 bf16), and K/V as
// fragment-ordered per-32kv-tile images (4KB each).
// K image: tile32*4096 + (kh*2+t)*1024 + (g*16+c)*16 + j*2
//          holds K[t*16+c][kh*32+g*8+j]                       (t = 16-row subtile)
// V image: tile32*4096 + td*1024 + (g*16+c)*16 + j*2
//          holds V[kvmap(g,j)][td*16+c], kvmap(g,j) = (j<4 ? 4g+j : 16+4g+j-4)
// kvmap is the K-dim permutation applied to BOTH PV operands: it makes each
// attn lane's exp2 outputs exactly its own PV A-fragment (zero redistribution).
#define XPAD 1040   // shorts per LDS row
__global__ __launch_bounds__(768) void proj_kernel(
        const float* __restrict__ x, const unsigned short* __restrict__ wb,
        const float* __restrict__ bb,
        unsigned short* __restrict__ qw, unsigned char* __restrict__ kimg,
        unsigned char* __restrict__ vimg) {
    __shared__ __align__(16) unsigned short xb[16][XPAD];
    int tid = threadIdx.x;
    int row0 = blockIdx.x * 16;

    if (tid < 512) {
        #pragma unroll
        for (int i = 0; i < 8; ++i) {
            int flat = i * 2048 + tid * 4;           // 16x1024 elems
            int r = flat >> 10, col = flat & 1023;
            float4 f = *(const float4*)(x + (size_t)(row0 + r) * EMB + col);
            uint2 p;
            p.x = cvt_pk_bf16(f.x, f.y);
            p.y = cvt_pk_bf16(f.z, f.w);
            *(uint2*)(&xb[r][col]) = p;
        }
    }
    __syncthreads();

    int wave = tid >> 6;            // 0..11 = output col-tile
    int lane = tid & 63;
    int c = lane & 15, g = lane >> 4;

    // two independent accumulator chains (halves the serial MFMA latency chain)
    f32x4 acc0 = {}, acc1 = {};
    const unsigned short* bp0 = wb + (size_t)(wave * 16 + c) * EMB;
    #pragma unroll 8
    for (int ks = 0; ks < 16; ++ks) {
        s16x8 a0 = *(const s16x8*)(&xb[c][ks * 32 + g * 8]);
        s16x8 b0 = *(const s16x8*)(bp0 + ks * 32 + g * 8);
        acc0 = __builtin_amdgcn_mfma_f32_16x16x32_bf16(a0, b0, acc0, 0, 0, 0);
        s16x8 a1 = *(const s16x8*)(&xb[c][(ks + 16) * 32 + g * 8]);
        s16x8 b1 = *(const s16x8*)(bp0 + (ks + 16) * 32 + g * 8);
        acc1 = __builtin_amdgcn_mfma_f32_16x16x32_bf16(a1, b1, acc1, 0, 0, 0);
    }
    float bias = bb[wave * 16 + c];
    f32x4 acc;
    acc[0] = acc0[0] + acc1[0] + bias;
    acc[1] = acc0[1] + acc1[1] + bias;
    acc[2] = acc0[2] + acc1[2] + bias;
    acc[3] = acc0[3] + acc1[3] + bias;

    size_t tile32 = (size_t)(row0 >> 5);
    int tI2 = (row0 >> 4) & 1;      // which 16-row subtile of the 32-kv tile

    if (wave < 4) {
        int col = wave * 16 + c;
        #pragma unroll
        for (int r = 0; r < 4; ++r)
            qw[(size_t)(row0 + g * 4 + r) * HD + col] = f2bf(acc[r]);
    } else if (wave < 8) {
        // K rows row0+g*4+r (subtile row cl=g*4+r), col C = (wave-4)*16+c
        int C = (wave - 4) * 16 + c;
        int kh = C >> 5;
        int gg = (C & 31) >> 3;
        int j = C & 7;
        unsigned char* base = kimg + tile32 * 4096 +
                              (size_t)((kh * 2 + tI2) * 1024 + j * 2);
        #pragma unroll
        for (int r = 0; r < 4; ++r) {
            int cl = g * 4 + r;
            *(unsigned short*)(base + (gg * 16 + cl) * 16) = f2bf(acc[r]);
        }
    } else {
        // V: d = (wave-8)*16+c, kv tokens row0+g*4+r -> kvmap slot (g, tI2*4+r)
        int td = wave - 8;
        uint2 pack;
        pack.x = cvt_pk_bf16(acc[0], acc[1]);
        pack.y = cvt_pk_bf16(acc[2], acc[3]);
        *(uint2*)(vimg + tile32 * 4096 +
                  (size_t)(td * 1024 + (g * 16 + c) * 16 + tI2 * 8)) = pack;
    }
}

// ---------------- attn: swapped-QK flash, no max, 2 q-tiles (32 rows) per wave,
// KVBLK=32. Block = 4 waves = 128 q-rows x one kv split; K/V tiles (4KB+4KB)
// staged block-wide into double-buffered LDS via global_load_lds. The kvmap
// permutation makes exp2 outputs lane-local PV A-frags: no swizzle/cndmask.
// launch_bounds(256,4): 4 blocks/CU resident, phase-offset overlap.
template <int S>
__global__ __launch_bounds__(256, 4) void attn_kernel(
        const unsigned short* __restrict__ qw, const unsigned char* __restrict__ kimg,
        const unsigned char* __restrict__ vimg,
        float* __restrict__ po, float* __restrict__ pl) {
    constexpr int KVS = TOK / S;
    constexpr int NIT = KVS / 32;        // 16 for S=16
    constexpr int QB = TOK / 128;        // 64 qblocks of 128 rows
    __shared__ __align__(16) unsigned char lds[2][8192];  // [buf][K 4KB | V 4KB]
    int wave = threadIdx.x >> 6;
    int lane = threadIdx.x & 63;
    int c = lane & 15, g = lane >> 4;
    int qb = blockIdx.x % QB;
    int split = blockIdx.x / QB;
    int wq0 = qb * 128 + wave * 32;      // this wave's 32 q-rows
    int tile0 = split * NIT;             // first 32-kv tile of this split

    // Q B-frags: 2 q-tiles x 2 k-halves (loop-invariant)
    s16x8 aq[2][2];
    #pragma unroll
    for (int qt = 0; qt < 2; ++qt)
        #pragma unroll
        for (int kh = 0; kh < 2; ++kh)
            aq[qt][kh] = *(const s16x8*)(qw + (size_t)(wq0 + qt * 16 + c) * HD + kh * 32 + g * 8);

    f32x4 o[2][4] = {};
    float l[2] = {};

    // staging: wave w copies 1KB of K image + 1KB of V image per tile
    auto stage = [&](int buf, int tile) {
        const unsigned char* kg = kimg + (size_t)tile * 4096;
        const unsigned char* vg = vimg + (size_t)tile * 4096;
        __builtin_amdgcn_global_load_lds(
            (const __attribute__((address_space(1))) void*)(kg + wave * 1024 + lane * 16),
            (__attribute__((address_space(3))) void*)(&lds[buf][wave * 1024]), 16, 0, 0);
        __builtin_amdgcn_global_load_lds(
            (const __attribute__((address_space(1))) void*)(vg + wave * 1024 + lane * 16),
            (__attribute__((address_space(3))) void*)(&lds[buf][4096 + wave * 1024]), 16, 0, 0);
    };

    stage(0, tile0);
    __syncthreads();     // compiler drains vmcnt before s_barrier

    int buf = 0;
    #pragma unroll 1
    for (int it = 0; it < NIT; ++it) {
        int nt = (it + 1 < NIT) ? it + 1 : it;   // clamp: last prefetch harmless
        stage(buf ^ 1, tile0 + nt);

        const unsigned char* Kl = &lds[buf][0];
        const unsigned char* Vl = &lds[buf][4096];

        // QK: S^T = K @ Q^T (st[q][t]: lane(c,g) reg r = S[kv=16t+4g+r][qrow=c])
        f32x4 st[2][2] = {};
        __builtin_amdgcn_s_setprio(1);
        #pragma unroll
        for (int kh = 0; kh < 2; ++kh) {
            s16x8 kf0 = *(const s16x8*)(Kl + (kh * 2 + 0) * 1024 + lane * 16);
            s16x8 kf1 = *(const s16x8*)(Kl + (kh * 2 + 1) * 1024 + lane * 16);
            #pragma unroll
            for (int q = 0; q < 2; ++q) {
                st[q][0] = __builtin_amdgcn_mfma_f32_16x16x32_bf16(kf0, aq[q][kh], st[q][0], 0, 0, 0);
                st[q][1] = __builtin_amdgcn_mfma_f32_16x16x32_bf16(kf1, aq[q][kh], st[q][1], 0, 0, 0);
            }
        }
        __builtin_amdgcn_s_setprio(0);

        // softmax numerators: p = exp2(s); pack directly into PV A-frags (kvmap)
        unsigned Wall[2][4];
        #pragma unroll
        for (int q = 0; q < 2; ++q) {
            float p[2][4];
            #pragma unroll
            for (int t = 0; t < 2; ++t)
                #pragma unroll
                for (int r = 0; r < 4; ++r)
                    p[t][r] = __builtin_amdgcn_exp2f(st[q][t][r]);
            float s0 = (p[0][0] + p[0][1]) + (p[0][2] + p[0][3]);
            float s1 = (p[1][0] + p[1][1]) + (p[1][2] + p[1][3]);
            l[q] += s0 + s1;
            Wall[q][0] = cvt_pk_bf16(p[0][0], p[0][1]);
            Wall[q][1] = cvt_pk_bf16(p[0][2], p[0][3]);
            Wall[q][2] = cvt_pk_bf16(p[1][0], p[1][1]);
            Wall[q][3] = cvt_pk_bf16(p[1][2], p[1][3]);
        }

        // PV: o[q][td] += P(16x32, kvmap order) @ V(32x16, same order)
        s16x8 vf[4];
        #pragma unroll
        for (int td = 0; td < 4; ++td)
            vf[td] = *(const s16x8*)(Vl + td * 1024 + lane * 16);
        __builtin_amdgcn_s_setprio(1);
        #pragma unroll
        for (int q = 0; q < 2; ++q) {
            s16x8 pa = frag4(Wall[q][0], Wall[q][1], Wall[q][2], Wall[q][3]);
            #pragma unroll
            for (int td = 0; td < 4; ++td)
                o[q][td] = __builtin_amdgcn_mfma_f32_16x16x32_bf16(pa, vf[td], o[q][td], 0, 0, 0);
        }
        __builtin_amdgcn_s_setprio(0);

        __syncthreads();
        buf ^= 1;
    }

    // epilogue: o[qt][td] row = g*4+r (q within tile), col = c (dv within tile td)
    #pragma unroll
    for (int qt = 0; qt < 2; ++qt) {
        #pragma unroll
        for (int td = 0; td < 4; ++td)
            #pragma unroll
            for (int r = 0; r < 4; ++r)
                po[((size_t)split * TOK + wq0 + qt * 16 + g * 4 + r) * HD + td * 16 + c] = o[qt][td][r];
        float v = l[qt];
        v += __shfl_xor(v, 16);
        v += __shfl_xor(v, 32);
        if (g == 0)
            pl[split * TOK + wq0 + qt * 16 + c] = v;
    }
}

// ---------------- combine: sum S splits, divide by total denom, tile x16 heads.
template <int S>
__global__ __launch_bounds__(256) void combine_kernel(
        const float* __restrict__ po, const float* __restrict__ pl,
        float* __restrict__ out) {
    int gid = blockIdx.x * 256 + threadIdx.x;   // 0 .. 8192*16-1
    int row = gid >> 4;
    int dc = (gid & 15) * 4;
    float4 acc = {0.f, 0.f, 0.f, 0.f};
    float denom = 0.f;
    #pragma unroll
    for (int s = 0; s < S; ++s) {
        denom += pl[s * TOK + row];
        float4 p = *(const float4*)(po + ((size_t)s * TOK + row) * HD + dc);
        acc.x += p.x; acc.y += p.y; acc.z += p.z; acc.w += p.w;
    }
    float inv = 1.0f / denom;
    acc.x *= inv; acc.y *= inv; acc.z *= inv; acc.w *= inv;
    #pragma unroll
    for (int h = 0; h < HEADS; ++h)
        *(float4*)(out + (size_t)row * EMB + h * HD + dc) = acc;
}

extern "C" void kernel_launch(void* const* d_in, const int* in_sizes, int n_in,
                              void* d_out, int out_size, void* d_ws, size_t ws_size,
                              hipStream_t stream) {
    const float* x  = (const float*)d_in[0];
    const float* Wq = (const float*)d_in[1];
    const float* bq = (const float*)d_in[2];
    const float* Wk = (const float*)d_in[3];
    const float* bk = (const float*)d_in[4];
    const float* Wv = (const float*)d_in[5];
    const float* bv = (const float*)d_in[6];
    float* out = (float*)d_out;
    char* ws = (char*)d_ws;
    unsigned short* wb   = (unsigned short*)(ws + 0x000000);  // 192x1024 bf16 = 384K
    float*          bb   = (float*)         (ws + 0x060000);  // 192 f32
    unsigned short* qw   = (unsigned short*)(ws + 0x061000);  // 8192x64 bf16 = 1M
    unsigned char*  kimg = (unsigned char*) (ws + 0x161000);  // 256 tiles x 4KB = 1M
    unsigned char*  vimg = (unsigned char*) (ws + 0x261000);  // 1M
    float*          po   = (float*)         (ws + 0x361000);  // S x 8192x64 f32 (2M each)

    prep_kernel<<<dim3(768), dim3(256), 0, stream>>>(Wq, bq, Wk, bk, Wv, bv, wb, bb);
    proj_kernel<<<dim3(512), dim3(768), 0, stream>>>(x, wb, bb, qw, kimg, vimg);

    const size_t base = 0x361000;
    const size_t per_split = (size_t)TOK * HD * 4;       // 2 MB po
    const size_t per_pl    = (size_t)TOK * 4;            // 32 KB
    auto need = [&](int s) { return base + (size_t)s * (per_split + per_pl); };

    if (ws_size >= need(16)) {
        float* pl = (float*)(ws + base + 16 * per_split);
        attn_kernel<16><<<dim3(64 * 16), dim3(256), 0, stream>>>(qw, kimg, vimg, po, pl);
        combine_kernel<16><<<dim3(512), dim3(256), 0, stream>>>(po, pl, out);
    } else {
        float* pl = (float*)(ws + base + 8 * per_split);
        attn_kernel<8><<<dim3(64 * 8), dim3(256), 0, stream>>>(qw, kimg, vimg, po, pl);
        combine_kernel<8><<<dim3(512), dim3(256), 0, stream>>>(po, pl, out);
    }
}